// Round 4
// baseline (2236.327 us; speedup 1.0000x reference)
//
#include <hip/hip_runtime.h>
#include <math.h>

// Problem constants
#define NB 512
#define NS 17
#define NL 81
#define NV 13030
#define NENC 240
#define NOE 80
#define NPE 60
#define NH 200
#define NIN 380
#define NG 800        // 4*H
#define KP 224        // padded K for scores GEMM (>=200, mult of 32)
#define KG 608        // padded K for gates GEMM: 224(h)+240(enc)+80(oe)+60(pe)+4
#define NVP 13056     // NV padded to 64 (204*64)
#define NGP 832       // NG padded to 64 (13*64)
#define NBLK 204      // NVP/64 n-blocks in scores grid
#define RPB 16        // rows per step_pre block (LDS = 16*804*4 = 51.5 KB < 64 KB)

// xh (activation) column layout, bf16, row stride KG:
//   [0:200) h   [200:224) zero   [224:464) loc_enc   [464:544) order_emb
//   [544:604) power_emb   [604:608) zero
#define XH_ENC 224
#define XH_OE  464
#define XH_PE  544

typedef short bf8_t __attribute__((ext_vector_type(8)));   // 8 bf16 (4 VGPRs)
typedef float f4_t __attribute__((ext_vector_type(4)));

__device__ __forceinline__ unsigned short f2bf(float f) {
  unsigned u = __float_as_uint(f);
  unsigned r = (u + 0x7fffu + ((u >> 16) & 1u)) >> 16;
  return (unsigned short)r;
}

// ---------------- threefry2x32 ----------------
__device__ __host__ __forceinline__ unsigned rotl32h(unsigned x, int d) {
  return (x << d) | (x >> (32 - d));
}
__device__ __host__ __forceinline__ void threefry2x32(
    unsigned k0, unsigned k1, unsigned x0, unsigned x1,
    unsigned& y0, unsigned& y1) {
  unsigned ks2 = k0 ^ k1 ^ 0x1BD11BDAu;
  x0 += k0; x1 += k1;
#define TFR(r) { x0 += x1; x1 = rotl32h(x1, r); x1 ^= x0; }
  TFR(13) TFR(15) TFR(26) TFR(6)
  x0 += k1;  x1 += ks2 + 1u;
  TFR(17) TFR(29) TFR(16) TFR(24)
  x0 += ks2; x1 += k0 + 2u;
  TFR(13) TFR(15) TFR(26) TFR(6)
  x0 += k0;  x1 += k1 + 3u;
  TFR(17) TFR(29) TFR(16) TFR(24)
  x0 += k1;  x1 += ks2 + 4u;
  TFR(13) TFR(15) TFR(26) TFR(6)
  x0 += ks2; x1 += k0 + 5u;
#undef TFR
  y0 = x0; y1 = x1;
}

__device__ __forceinline__ float gumbel_from_bits(unsigned bits) {
  float u = __uint_as_float((bits >> 9) | 0x3f800000u) - 1.0f;
  if (u == 0.0f) u = 1.17549435e-38f;
  return -__logf(-__logf(u));
}

// ---------------- one-time prep kernels (baseline-proven) ----------------
__global__ void __launch_bounds__(256) prep_wcat_kernel(
    const float* __restrict__ W_ih, const float* __restrict__ W_hh,
    unsigned short* __restrict__ Wcat) {
  int t = blockIdx.x * 256 + threadIdx.x;
  if (t >= NGP * KG) return;
  int n = t / KG, k = t % KG;
  float v = 0.f;
  if (n < NG) {
    if (k < NH) v = W_hh[n * NH + k];
    else if (k >= XH_ENC && k < XH_PE + NPE) v = W_ih[n * NIN + (k - XH_ENC)];
  }
  Wcat[t] = f2bf(v);
}

__global__ void __launch_bounds__(256) prep_outw_kernel(
    const float* __restrict__ out_W, unsigned short* __restrict__ outWb) {
  int t = blockIdx.x * 256 + threadIdx.x;
  if (t >= NVP * KP) return;
  int n = t / KP, k = t % KP;
  outWb[t] = f2bf((n < NV && k < NH) ? out_W[n * NH + k] : 0.f);
}

__global__ void __launch_bounds__(256) misc_kernel(
    const float* __restrict__ power_1h, const float* __restrict__ power_W,
    const float* __restrict__ power_b, const int* __restrict__ loc_idxs,
    const float* __restrict__ b_ih, const float* __restrict__ b_hh,
    unsigned short* __restrict__ xh, float* __restrict__ bcat,
    int* __restrict__ invalid) {
  int t = blockIdx.x * 256 + threadIdx.x;
  if (t < NB * NPE) {
    int b = t / NPE, p = t % NPE;
    float a = power_b[p];
#pragma unroll
    for (int k = 0; k < 7; ++k) a = fmaf(power_1h[b * 7 + k], power_W[p * 7 + k], a);
    xh[(size_t)b * KG + XH_PE + p] = f2bf(a);
  }
  if (t < NG) bcat[t] = b_ih[t] + b_hh[t];
  if (t < NB) {
    bool any = false;
    for (int l = 0; l < NL; ++l) any = any || (loc_idxs[t * NL + l] != -1);
    invalid[t] = any ? 0 : 1;
  }
}

// ---------------- per-step: alignment + loc_enc into xh (baseline-proven) ---
__global__ void __launch_bounds__(256) build_x_kernel(
    const int* __restrict__ loc_idxs, const float* __restrict__ MA,
    const float* __restrict__ enc, unsigned short* __restrict__ xh, int step) {
  __shared__ float sel[NL];
  __shared__ float aln[NL];
  __shared__ float denom;
  const int b = blockIdx.x, tid = threadIdx.x;
  if (tid < NL) {
    int li = loc_idxs[b * NL + tid];
    sel[tid] = (li == step || li == -2) ? 1.0f : 0.0f;
  }
  __syncthreads();
  if (tid < NL) {
    float a = 0.f;
    for (int l = 0; l < NL; ++l) a = fmaf(sel[l], MA[l * NL + tid], a);
    aln[tid] = a;
  }
  __syncthreads();
  if (tid == 0) {
    float d = 0.f;
    for (int l = 0; l < NL; ++l) d += aln[l];
    denom = d;
  }
  __syncthreads();
  if (tid < NL) aln[tid] = (denom != 0.f) ? aln[tid] / denom : 0.0f;
  __syncthreads();
  if (tid < NENC) {
    const float* eb = enc + (size_t)b * NL * NENC + tid;
    float a = 0.f;
    for (int l = 0; l < NL; ++l) a = fmaf(aln[l], eb[(size_t)l * NENC], a);
    xh[(size_t)b * KG + XH_ENC + tid] = f2bf(a);
  }
}

// ---------------- MFMA NT GEMM core: per-wave 16x64 tile --------------------
__device__ __forceinline__ void mfma_nt_16x64(
    const unsigned short* __restrict__ A, const unsigned short* __restrict__ B,
    int lda, int ldb, int m0w, int n0, int nk, f4_t acc[4]) {
  const int lane = threadIdx.x & 63;
  const int tx = lane & 15, quad = lane >> 4;
  const unsigned short* ap = A + (size_t)(m0w + tx) * lda + quad * 8;
  const unsigned short* bp0 = B + (size_t)(n0 + tx) * ldb + quad * 8;
  for (int kc = 0; kc < nk; ++kc) {
    bf8_t a = *(const bf8_t*)(ap + kc * 32);
#pragma unroll
    for (int jf = 0; jf < 4; ++jf) {
      bf8_t b = *(const bf8_t*)(bp0 + (size_t)jf * 16 * ldb + kc * 32);
      acc[jf] = __builtin_amdgcn_mfma_f32_16x16x32_bf16(a, b, acc[jf], 0, 0, 0);
    }
  }
}

// ---- per-step fused: finalize prev sample + gates GEMM (LDS) + LSTM --------
// grid: NB/RPB = 32 blocks x 256 threads; block owns rows [m0, m0+16).
// All 4 waves compute the same 16 rows, striding the 13 column tiles.
__global__ void __launch_bounds__(256) step_pre_kernel(
    const float* __restrict__ pval, const int* __restrict__ pidx,
    const float* __restrict__ order_embedding,
    const unsigned short* __restrict__ Wcat, const float* __restrict__ bcat,
    unsigned short* __restrict__ xh, float* __restrict__ c,
    float* __restrict__ out, int step) {
  const int m0 = blockIdx.x * RPB;
  const int tid = threadIdx.x;
  __shared__ float sG[RPB][NG + 4];   // 16*804*4 = 51.5 KB
  __shared__ int sIdx[RPB];

  // ---- Phase A: finalize previous step's sample for own rows (uniform branch)
  if (step > 0) {
    const int r = tid >> 4, u = tid & 15;   // 16 rows x 16 threads
    const int m = m0 + r;
    float bv = -INFINITY; int bi = 0x7fffffff;
    for (int j = u; j < NBLK; j += 16) {
      float v = pval[(size_t)m * NBLK + j];
      int   i = pidx[(size_t)m * NBLK + j];
      if (v > bv || (v == bv && i < bi)) { bv = v; bi = i; }
    }
#pragma unroll
    for (int s = 8; s >= 1; s >>= 1) {
      float ov = __shfl_xor(bv, s);
      int   oi = __shfl_xor(bi, s);
      if (ov > bv || (ov == bv && oi < bi)) { bv = ov; bi = oi; }
    }
    if (u == 0) {
      sIdx[r] = bi;
      out[(size_t)m * NS + (step - 1)] = (float)bi;
    }
    __syncthreads();
    // gather order embeddings into xh (own rows only)
    for (int e = tid; e < RPB * NOE; e += 256) {
      int rr = e / NOE, k = e % NOE;
      xh[(size_t)(m0 + rr) * KG + XH_OE + k] =
          f2bf(order_embedding[(size_t)sIdx[rr] * NOE + k]);
    }
    __syncthreads();
  }

  // ---- Phase B: gates GEMM (16 rows x 832 cols) -> LDS
  const int w = tid >> 6, lane = tid & 63;
  const int tx = lane & 15, quad = lane >> 4;
  for (int tile = w; tile < NGP / 64; tile += 4) {
    f4_t acc[4] = {};
    mfma_nt_16x64(xh, Wcat, KG, KG, m0, tile * 64, KG / 32, acc);
#pragma unroll
    for (int jf = 0; jf < 4; ++jf) {
      int n = tile * 64 + jf * 16 + tx;
      if (n >= NG) continue;
      float bias = bcat[n];
#pragma unroll
      for (int reg = 0; reg < 4; ++reg)
        sG[quad * 4 + reg][n] = acc[jf][reg] + bias;
    }
  }
  __syncthreads();

  // ---- Phase C: LSTM cell, h -> xh (bf16), c updated in-place
  for (int e = tid; e < RPB * NH; e += 256) {
    int rr = e / NH, j = e % NH;
    int m = m0 + rr;
    float gi = sG[rr][j], gf = sG[rr][NH + j];
    float gg = sG[rr][2 * NH + j], go = sG[rr][3 * NH + j];
    float si = 1.f / (1.f + expf(-gi));
    float sf = 1.f / (1.f + expf(-gf));
    float so = 1.f / (1.f + expf(-go));
    float cn = sf * c[(size_t)m * NH + j] + si * tanhf(gg);
    float hn = so * tanhf(cn);
    c[(size_t)m * NH + j] = cn;
    xh[(size_t)m * KG + j] = f2bf(hn);
  }
}

// ------ per-step: scores GEMM + mask + write + gumbel + partial argmax ------
__global__ void __launch_bounds__(256) scores_kernel(
    const unsigned short* __restrict__ xh, const unsigned short* __restrict__ outWb,
    const float* __restrict__ out_b, const int* __restrict__ order_masks,
    const int* __restrict__ invalid, float* __restrict__ out,
    float* __restrict__ pval, int* __restrict__ pidx,
    int step, unsigned k0, unsigned k1) {
  const int w = threadIdx.x >> 6;
  const int lane = threadIdx.x & 63;
  const int tx = lane & 15, quad = lane >> 4;
  const int m0w = blockIdx.y * 64 + w * 16;
  const int n0 = blockIdx.x * 64;
  f4_t acc[4] = {};
  mfma_nt_16x64(xh, outWb, KG, KP, m0w, n0, KP / 32, acc);

  float bias[4];
  int nn[4];
#pragma unroll
  for (int jf = 0; jf < 4; ++jf) {
    nn[jf] = n0 + jf * 16 + tx;
    bias[jf] = (nn[jf] < NV) ? out_b[nn[jf]] : 0.f;
  }

  float bval[4];
  int bidx[4];
#pragma unroll
  for (int reg = 0; reg < 4; ++reg) {
    const int m = m0w + quad * 4 + reg;
    const int inv = invalid[m];
    const int* mrow = order_masks + (size_t)m * NS * NV + (size_t)step * NV;
    float* orow = out + (size_t)NB * NS + ((size_t)m * NS + step) * (size_t)NV;
    float vals[4];
#pragma unroll
    for (int jf = 0; jf < 4; ++jf) {
      int n = nn[jf];
      float v = -1.0e8f;
      if (n < NV) {
        int msk = inv ? 1 : mrow[n];
        v = fminf(acc[jf][reg] + bias[jf], msk ? 9.0e8f : -1.0e8f);
        orow[n] = v;
      }
      vals[jf] = v;
    }
    // gumbel (threefry pairs over jf: (0,1) and (2,3))
    unsigned base = (unsigned)m * (unsigned)NV;
    unsigned y0, y1, y2, y3;
    threefry2x32(k0, k1, base + (unsigned)nn[0], base + (unsigned)nn[1], y0, y1);
    threefry2x32(k0, k1, base + (unsigned)nn[2], base + (unsigned)nn[3], y2, y3);
    float g[4] = {gumbel_from_bits(y0), gumbel_from_bits(y1),
                  gumbel_from_bits(y2), gumbel_from_bits(y3)};
    float bv = -INFINITY; int bi = 0;
#pragma unroll
    for (int jf = 0; jf < 4; ++jf) {
      float cnd = (nn[jf] < NV) ? vals[jf] + g[jf] : -INFINITY;
      if (cnd > bv) { bv = cnd; bi = nn[jf]; }
    }
    bval[reg] = bv; bidx[reg] = bi;
  }
  // reduce across the 16 lanes of this quad (xor 1,2,4,8 stays in-group)
#pragma unroll
  for (int s = 8; s >= 1; s >>= 1) {
#pragma unroll
    for (int reg = 0; reg < 4; ++reg) {
      float ov = __shfl_xor(bval[reg], s);
      int oi = __shfl_xor(bidx[reg], s);
      if (ov > bval[reg]) { bval[reg] = ov; bidx[reg] = oi; }
    }
  }
#pragma unroll
  for (int reg = 0; reg < 4; ++reg) {
    if (tx == reg) {
      int m = m0w + quad * 4 + reg;
      pval[(size_t)m * NBLK + blockIdx.x] = bval[reg];
      pidx[(size_t)m * NBLK + blockIdx.x] = bidx[reg];
    }
  }
}

// ---------------- after loop: finalize the last step's sample ----------------
__global__ void __launch_bounds__(256) final_sample_kernel(
    const float* __restrict__ pval, const int* __restrict__ pidx,
    float* __restrict__ out) {
  const int m0 = blockIdx.x * RPB;
  const int tid = threadIdx.x;
  const int r = tid >> 4, u = tid & 15;
  const int m = m0 + r;
  float bv = -INFINITY; int bi = 0x7fffffff;
  for (int j = u; j < NBLK; j += 16) {
    float v = pval[(size_t)m * NBLK + j];
    int   i = pidx[(size_t)m * NBLK + j];
    if (v > bv || (v == bv && i < bi)) { bv = v; bi = i; }
  }
#pragma unroll
  for (int s = 8; s >= 1; s >>= 1) {
    float ov = __shfl_xor(bv, s);
    int   oi = __shfl_xor(bi, s);
    if (ov > bv || (ov == bv && oi < bi)) { bv = ov; bi = oi; }
  }
  if (u == 0) out[(size_t)m * NS + (NS - 1)] = (float)bi;
}

extern "C" void kernel_launch(void* const* d_in, const int* in_sizes, int n_in,
                              void* d_out, int out_size, void* d_ws, size_t ws_size,
                              hipStream_t stream) {
  const float* enc          = (const float*)d_in[0];
  const int*   loc_idxs     = (const int*)d_in[2];
  const int*   order_masks  = (const int*)d_in[3];
  const float* power_1h     = (const float*)d_in[4];
  const float* order_embedding = (const float*)d_in[5];
  const float* power_W      = (const float*)d_in[6];
  const float* power_b      = (const float*)d_in[7];
  const float* W_ih         = (const float*)d_in[8];
  const float* W_hh         = (const float*)d_in[9];
  const float* b_ih         = (const float*)d_in[10];
  const float* b_hh         = (const float*)d_in[11];
  const float* out_W        = (const float*)d_in[12];
  const float* out_b        = (const float*)d_in[13];
  const float* MA           = (const float*)d_in[14];

  // Workspace layout: byte-identical to the proven baseline (gates kept as pad)
  float* ws      = (float*)d_ws;
  float* c       = ws;                      // NB*NH
  float* gates   = c + NB * NH;             // NB*NG (unused; layout padding)
  float* pval    = gates + NB * NG;         // NB*NBLK
  float* bcat    = pval + NB * NBLK;        // NG
  int*   pidx    = (int*)(bcat + NG);       // NB*NBLK
  int*   invalid = pidx + NB * NBLK;        // NB
  unsigned short* xh    = (unsigned short*)(invalid + NB);  // NB*KG bf16
  unsigned short* Wcat  = xh + (size_t)NB * KG;             // NGP*KG bf16
  unsigned short* outWb = Wcat + (size_t)NGP * KG;          // NVP*KP bf16
  (void)gates;

  float* out = (float*)d_out;

  // zero recurrent state: xh (h/oe/pads) + c  (baseline-proven)
  hipMemsetAsync(xh, 0, sizeof(unsigned short) * (size_t)NB * KG, stream);
  hipMemsetAsync(c, 0, sizeof(float) * (size_t)NB * NH, stream);
  misc_kernel<<<(NB * NPE + 255) / 256, 256, 0, stream>>>(
      power_1h, power_W, power_b, loc_idxs, b_ih, b_hh, xh, bcat, invalid);
  prep_wcat_kernel<<<(NGP * KG + 255) / 256, 256, 0, stream>>>(W_ih, W_hh, Wcat);
  prep_outw_kernel<<<(NVP * KP + 255) / 256, 256, 0, stream>>>(out_W, outWb);

  // step keys (host-side threefry: deterministic, no device API)
  unsigned key[2 * NS];
  for (unsigned i = 0; i < NS; ++i) {
    unsigned y0, y1;
    threefry2x32(0u, 42u, i, i + NS, y0, y1);
    key[2 * i] = y0;
    threefry2x32(0u, 42u, i, i + NS, y0, y1);  // same block; lane1 of pair (i, i+NS)
    key[2 * i + 1] = y1;
  }

  dim3 gScores(NBLK, NB / 64);
  for (int s = 0; s < NS; ++s) {
    build_x_kernel<<<NB, 256, 0, stream>>>(loc_idxs, MA, enc, xh, s);
    step_pre_kernel<<<NB / RPB, 256, 0, stream>>>(
        pval, pidx, order_embedding, Wcat, bcat, xh, c, out, s);
    scores_kernel<<<gScores, 256, 0, stream>>>(
        xh, outWb, out_b, order_masks, invalid, out, pval, pidx,
        s, key[2 * s], key[2 * s + 1]);
  }
  final_sample_kernel<<<NB / RPB, 256, 0, stream>>>(pval, pidx, out);
}

// Round 5
// 1835.648 us; speedup vs baseline: 1.2183x; 1.2183x over previous
//
#include <hip/hip_runtime.h>
#include <math.h>

// Problem constants
#define NB 512
#define NS 17
#define NL 81
#define NV 13030
#define NENC 240
#define NOE 80
#define NPE 60
#define NH 200
#define NIN 380
#define NG 800        // 4*H
#define KP 224        // padded K for scores GEMM (>=200, mult of 32)
#define KG 608        // padded K for gates GEMM: 224(h)+240(enc)+80(oe)+60(pe)+4
#define NVP 13056     // NV padded to 64 (204*64)
#define NGP 832       // NG padded to 64 (13*64)
#define NBLK 204      // NVP/64 n-blocks in scores grid

// xh (activation) column layout, bf16, row stride KG:
//   [0:200) h   [200:224) zero   [224:464) loc_enc   [464:544) order_emb
//   [544:604) power_emb   [604:608) zero
#define XH_ENC 224
#define XH_OE  464
#define XH_PE  544

typedef short bf8_t __attribute__((ext_vector_type(8)));   // 8 bf16 (4 VGPRs)
typedef float f4_t __attribute__((ext_vector_type(4)));

__device__ __forceinline__ unsigned short f2bf(float f) {
  unsigned u = __float_as_uint(f);
  unsigned r = (u + 0x7fffu + ((u >> 16) & 1u)) >> 16;
  return (unsigned short)r;
}

// ---------------- threefry2x32 ----------------
__device__ __host__ __forceinline__ unsigned rotl32h(unsigned x, int d) {
  return (x << d) | (x >> (32 - d));
}
__device__ __host__ __forceinline__ void threefry2x32(
    unsigned k0, unsigned k1, unsigned x0, unsigned x1,
    unsigned& y0, unsigned& y1) {
  unsigned ks2 = k0 ^ k1 ^ 0x1BD11BDAu;
  x0 += k0; x1 += k1;
#define TFR(r) { x0 += x1; x1 = rotl32h(x1, r); x1 ^= x0; }
  TFR(13) TFR(15) TFR(26) TFR(6)
  x0 += k1;  x1 += ks2 + 1u;
  TFR(17) TFR(29) TFR(16) TFR(24)
  x0 += ks2; x1 += k0 + 2u;
  TFR(13) TFR(15) TFR(26) TFR(6)
  x0 += k0;  x1 += k1 + 3u;
  TFR(17) TFR(29) TFR(16) TFR(24)
  x0 += k1;  x1 += ks2 + 4u;
  TFR(13) TFR(15) TFR(26) TFR(6)
  x0 += ks2; x1 += k0 + 5u;
#undef TFR
  y0 = x0; y1 = x1;
}

__device__ __forceinline__ float gumbel_from_bits(unsigned bits) {
  float u = __uint_as_float((bits >> 9) | 0x3f800000u) - 1.0f;
  if (u == 0.0f) u = 1.17549435e-38f;
  return -__logf(-__logf(u));
}

// ---------------- one-time prep kernels (baseline-proven) ----------------
__global__ void __launch_bounds__(256) prep_wcat_kernel(
    const float* __restrict__ W_ih, const float* __restrict__ W_hh,
    unsigned short* __restrict__ Wcat) {
  int t = blockIdx.x * 256 + threadIdx.x;
  if (t >= NGP * KG) return;
  int n = t / KG, k = t % KG;
  float v = 0.f;
  if (n < NG) {
    if (k < NH) v = W_hh[n * NH + k];
    else if (k >= XH_ENC && k < XH_PE + NPE) v = W_ih[n * NIN + (k - XH_ENC)];
  }
  Wcat[t] = f2bf(v);
}

__global__ void __launch_bounds__(256) prep_outw_kernel(
    const float* __restrict__ out_W, unsigned short* __restrict__ outWb) {
  int t = blockIdx.x * 256 + threadIdx.x;
  if (t >= NVP * KP) return;
  int n = t / KP, k = t % KP;
  outWb[t] = f2bf((n < NV && k < NH) ? out_W[n * NH + k] : 0.f);
}

__global__ void __launch_bounds__(256) misc_kernel(
    const float* __restrict__ power_1h, const float* __restrict__ power_W,
    const float* __restrict__ power_b, const int* __restrict__ loc_idxs,
    const float* __restrict__ b_ih, const float* __restrict__ b_hh,
    unsigned short* __restrict__ xh, float* __restrict__ bcat,
    int* __restrict__ invalid) {
  int t = blockIdx.x * 256 + threadIdx.x;
  if (t < NB * NPE) {
    int b = t / NPE, p = t % NPE;
    float a = power_b[p];
#pragma unroll
    for (int k = 0; k < 7; ++k) a = fmaf(power_1h[b * 7 + k], power_W[p * 7 + k], a);
    xh[(size_t)b * KG + XH_PE + p] = f2bf(a);
  }
  if (t < NG) bcat[t] = b_ih[t] + b_hh[t];
  if (t < NB) {
    bool any = false;
    for (int l = 0; l < NL; ++l) any = any || (loc_idxs[t * NL + l] != -1);
    invalid[t] = any ? 0 : 1;
  }
}

// -------- Path A one-time: alignment + loc_enc for ALL 17 steps -------------
// Bitwise-identical fmaf ordering to build_x_kernel. Also writes step-0 slice
// directly into xh. locenc layout: [NS][NB][NENC] bf16.
__global__ void __launch_bounds__(256) locenc_kernel(
    const int* __restrict__ loc_idxs, const float* __restrict__ MA,
    const float* __restrict__ enc, unsigned short* __restrict__ locenc,
    unsigned short* __restrict__ xh) {
  const int b = blockIdx.x, tid = threadIdx.x;
  __shared__ float sMA[NL * NL];     // 26.2 KB
  __shared__ float sAln[NS][NL];     // 5.5 KB
  __shared__ float sDen[NS];
  __shared__ int sLi[NL];
  if (tid < NL) sLi[tid] = loc_idxs[b * NL + tid];
  for (int e = tid; e < NL * NL; e += 256) sMA[e] = MA[e];
  __syncthreads();
  for (int e = tid; e < NS * NL; e += 256) {
    int s = e / NL, j = e % NL;
    float a = 0.f;
    for (int l = 0; l < NL; ++l) {
      float sel = (sLi[l] == s || sLi[l] == -2) ? 1.0f : 0.0f;
      a = fmaf(sel, sMA[l * NL + j], a);
    }
    sAln[s][j] = a;
  }
  __syncthreads();
  if (tid < NS) {
    float d = 0.f;
    for (int l = 0; l < NL; ++l) d += sAln[tid][l];
    sDen[tid] = d;
  }
  __syncthreads();
  for (int e = tid; e < NS * NL; e += 256) {
    int s = e / NL, j = e % NL;
    sAln[s][j] = (sDen[s] != 0.f) ? sAln[s][j] / sDen[s] : 0.f;
  }
  __syncthreads();
  if (tid < NENC) {
    float acc[NS];
#pragma unroll
    for (int s = 0; s < NS; ++s) acc[s] = 0.f;
    const float* eb = enc + (size_t)b * NL * NENC + tid;
    for (int l = 0; l < NL; ++l) {
      float e = eb[(size_t)l * NENC];
#pragma unroll
      for (int s = 0; s < NS; ++s) acc[s] = fmaf(sAln[s][l], e, acc[s]);
    }
#pragma unroll
    for (int s = 0; s < NS; ++s) {
      unsigned short v = f2bf(acc[s]);
      locenc[((size_t)s * NB + b) * NENC + tid] = v;
      if (s == 0) xh[(size_t)b * KG + XH_ENC + tid] = v;
    }
  }
}

// -------- Path B per-step: alignment + loc_enc into xh (baseline-proven) ----
__global__ void __launch_bounds__(256) build_x_kernel(
    const int* __restrict__ loc_idxs, const float* __restrict__ MA,
    const float* __restrict__ enc, unsigned short* __restrict__ xh, int step) {
  __shared__ float sel[NL];
  __shared__ float aln[NL];
  __shared__ float denom;
  const int b = blockIdx.x, tid = threadIdx.x;
  if (tid < NL) {
    int li = loc_idxs[b * NL + tid];
    sel[tid] = (li == step || li == -2) ? 1.0f : 0.0f;
  }
  __syncthreads();
  if (tid < NL) {
    float a = 0.f;
    for (int l = 0; l < NL; ++l) a = fmaf(sel[l], MA[l * NL + tid], a);
    aln[tid] = a;
  }
  __syncthreads();
  if (tid == 0) {
    float d = 0.f;
    for (int l = 0; l < NL; ++l) d += aln[l];
    denom = d;
  }
  __syncthreads();
  if (tid < NL) aln[tid] = (denom != 0.f) ? aln[tid] / denom : 0.0f;
  __syncthreads();
  if (tid < NENC) {
    const float* eb = enc + (size_t)b * NL * NENC + tid;
    float a = 0.f;
    for (int l = 0; l < NL; ++l) a = fmaf(aln[l], eb[(size_t)l * NENC], a);
    xh[(size_t)b * KG + XH_ENC + tid] = f2bf(a);
  }
}

// ---------------- MFMA NT GEMM core: per-wave 16x64 tile --------------------
__device__ __forceinline__ void mfma_nt_16x64(
    const unsigned short* __restrict__ A, const unsigned short* __restrict__ B,
    int lda, int ldb, int m0w, int n0, int nk, f4_t acc[4]) {
  const int lane = threadIdx.x & 63;
  const int tx = lane & 15, quad = lane >> 4;
  const unsigned short* ap = A + (size_t)(m0w + tx) * lda + quad * 8;
  const unsigned short* bp0 = B + (size_t)(n0 + tx) * ldb + quad * 8;
  for (int kc = 0; kc < nk; ++kc) {
    bf8_t a = *(const bf8_t*)(ap + kc * 32);
#pragma unroll
    for (int jf = 0; jf < 4; ++jf) {
      bf8_t b = *(const bf8_t*)(bp0 + (size_t)jf * 16 * ldb + kc * 32);
      acc[jf] = __builtin_amdgcn_mfma_f32_16x16x32_bf16(a, b, acc[jf], 0, 0, 0);
    }
  }
}

// ---------------- per-step: gates GEMM (M=512,N=800,K=608) ------------------
__global__ void __launch_bounds__(256) gates_kernel(
    const unsigned short* __restrict__ xh, const unsigned short* __restrict__ Wcat,
    const float* __restrict__ bcat, float* __restrict__ gates) {
  const int w = threadIdx.x >> 6;
  const int lane = threadIdx.x & 63;
  const int tx = lane & 15, quad = lane >> 4;
  const int m0w = blockIdx.y * 64 + w * 16;
  const int n0 = blockIdx.x * 64;
  f4_t acc[4] = {};
  mfma_nt_16x64(xh, Wcat, KG, KG, m0w, n0, KG / 32, acc);
#pragma unroll
  for (int jf = 0; jf < 4; ++jf) {
    int n = n0 + jf * 16 + tx;
    if (n >= NG) continue;
    float bias = bcat[n];
#pragma unroll
    for (int reg = 0; reg < 4; ++reg) {
      int m = m0w + quad * 4 + reg;
      gates[(size_t)m * NG + n] = acc[jf][reg] + bias;
    }
  }
}

// ---------------- per-step: LSTM cell; h -> xh bf16 ----------------
__global__ void __launch_bounds__(256) lstm_cell_kernel(
    const float* __restrict__ gates, unsigned short* __restrict__ xh,
    float* __restrict__ c) {
  int t = blockIdx.x * 256 + threadIdx.x;
  if (t >= NB * NH) return;
  int b = t / NH, j = t % NH;
  const float* g = gates + (size_t)b * NG;
  float gi = g[j], gf = g[NH + j], gg = g[2 * NH + j], go = g[3 * NH + j];
  float si = 1.f / (1.f + expf(-gi));
  float sf = 1.f / (1.f + expf(-gf));
  float so = 1.f / (1.f + expf(-go));
  float cn = sf * c[t] + si * tanhf(gg);
  float hn = so * tanhf(cn);
  c[t] = cn;
  xh[(size_t)b * KG + j] = f2bf(hn);
}

// ------ per-step: scores GEMM + mask + write + gumbel + partial argmax ------
__global__ void __launch_bounds__(256) scores_kernel(
    const unsigned short* __restrict__ xh, const unsigned short* __restrict__ outWb,
    const float* __restrict__ out_b, const int* __restrict__ order_masks,
    const int* __restrict__ invalid, float* __restrict__ out,
    float* __restrict__ pval, int* __restrict__ pidx,
    int step, unsigned k0, unsigned k1) {
  const int w = threadIdx.x >> 6;
  const int lane = threadIdx.x & 63;
  const int tx = lane & 15, quad = lane >> 4;
  const int m0w = blockIdx.y * 64 + w * 16;
  const int n0 = blockIdx.x * 64;
  f4_t acc[4] = {};
  mfma_nt_16x64(xh, outWb, KG, KP, m0w, n0, KP / 32, acc);

  float bias[4];
  int nn[4];
#pragma unroll
  for (int jf = 0; jf < 4; ++jf) {
    nn[jf] = n0 + jf * 16 + tx;
    bias[jf] = (nn[jf] < NV) ? out_b[nn[jf]] : 0.f;
  }

  float bval[4];
  int bidx[4];
#pragma unroll
  for (int reg = 0; reg < 4; ++reg) {
    const int m = m0w + quad * 4 + reg;
    const int inv = invalid[m];
    const int* mrow = order_masks + (size_t)m * NS * NV + (size_t)step * NV;
    float* orow = out + (size_t)NB * NS + ((size_t)m * NS + step) * (size_t)NV;
    float vals[4];
#pragma unroll
    for (int jf = 0; jf < 4; ++jf) {
      int n = nn[jf];
      float v = -1.0e8f;
      if (n < NV) {
        int msk = inv ? 1 : mrow[n];
        v = fminf(acc[jf][reg] + bias[jf], msk ? 9.0e8f : -1.0e8f);
        orow[n] = v;
      }
      vals[jf] = v;
    }
    // gumbel (threefry pairs over jf: (0,1) and (2,3))
    unsigned base = (unsigned)m * (unsigned)NV;
    unsigned y0, y1, y2, y3;
    threefry2x32(k0, k1, base + (unsigned)nn[0], base + (unsigned)nn[1], y0, y1);
    threefry2x32(k0, k1, base + (unsigned)nn[2], base + (unsigned)nn[3], y2, y3);
    float g[4] = {gumbel_from_bits(y0), gumbel_from_bits(y1),
                  gumbel_from_bits(y2), gumbel_from_bits(y3)};
    float bv = -INFINITY; int bi = 0;
#pragma unroll
    for (int jf = 0; jf < 4; ++jf) {
      float cnd = (nn[jf] < NV) ? vals[jf] + g[jf] : -INFINITY;
      if (cnd > bv) { bv = cnd; bi = nn[jf]; }
    }
    bval[reg] = bv; bidx[reg] = bi;
  }
  // reduce across the 16 lanes of this quad (xor 1,2,4,8 stays in-group)
#pragma unroll
  for (int s = 8; s >= 1; s >>= 1) {
#pragma unroll
    for (int reg = 0; reg < 4; ++reg) {
      float ov = __shfl_xor(bval[reg], s);
      int oi = __shfl_xor(bidx[reg], s);
      if (ov > bval[reg]) { bval[reg] = ov; bidx[reg] = oi; }
    }
  }
#pragma unroll
  for (int reg = 0; reg < 4; ++reg) {
    if (tx == reg) {
      int m = m0w + quad * 4 + reg;
      pval[(size_t)m * NBLK + blockIdx.x] = bval[reg];
      pidx[(size_t)m * NBLK + blockIdx.x] = bidx[reg];
    }
  }
}

// ---- per-step: final argmax reduce + embedding gather (+ next-step ENC) ----
__global__ void __launch_bounds__(256) sample_kernel(
    const float* __restrict__ pval, const int* __restrict__ pidx,
    const float* __restrict__ order_embedding,
    const unsigned short* __restrict__ locenc,  // null -> Path B (no ENC copy)
    unsigned short* __restrict__ xh, float* __restrict__ out, int step) {
  const int m = blockIdx.x, tid = threadIdx.x;
  __shared__ float sv[256];
  __shared__ int si[256];
  float v = -INFINITY; int i = 0;
  if (tid < NBLK) { v = pval[(size_t)m * NBLK + tid]; i = pidx[(size_t)m * NBLK + tid]; }
  sv[tid] = v; si[tid] = i;
  __syncthreads();
  for (int off = 128; off > 0; off >>= 1) {
    if (tid < off) {
      float v2 = sv[tid + off]; int i2 = si[tid + off];
      if (v2 > sv[tid] || (v2 == sv[tid] && i2 < si[tid])) { sv[tid] = v2; si[tid] = i2; }
    }
    __syncthreads();
  }
  if (tid == 0) out[m * NS + step] = (float)si[0];
  if (tid < NOE) {
    int idx = si[0];
    xh[(size_t)m * KG + XH_OE + tid] = f2bf(order_embedding[(size_t)idx * NOE + tid]);
  }
  // Path A: stage next step's loc_enc into xh (scores only reads cols [0,224))
  if (locenc != nullptr && step + 1 < NS && tid < NENC) {
    xh[(size_t)m * KG + XH_ENC + tid] =
        locenc[((size_t)(step + 1) * NB + m) * NENC + tid];
  }
}

extern "C" void kernel_launch(void* const* d_in, const int* in_sizes, int n_in,
                              void* d_out, int out_size, void* d_ws, size_t ws_size,
                              hipStream_t stream) {
  const float* enc          = (const float*)d_in[0];
  const int*   loc_idxs     = (const int*)d_in[2];
  const int*   order_masks  = (const int*)d_in[3];
  const float* power_1h     = (const float*)d_in[4];
  const float* order_embedding = (const float*)d_in[5];
  const float* power_W      = (const float*)d_in[6];
  const float* power_b      = (const float*)d_in[7];
  const float* W_ih         = (const float*)d_in[8];
  const float* W_hh         = (const float*)d_in[9];
  const float* b_ih         = (const float*)d_in[10];
  const float* b_hh         = (const float*)d_in[11];
  const float* out_W        = (const float*)d_in[12];
  const float* out_b        = (const float*)d_in[13];
  const float* MA           = (const float*)d_in[14];

  // Workspace layout: byte-identical to the proven baseline; locenc appended.
  float* ws      = (float*)d_ws;
  float* c       = ws;                      // NB*NH
  float* gates   = c + NB * NH;             // NB*NG
  float* pval    = gates + NB * NG;         // NB*NBLK
  float* bcat    = pval + NB * NBLK;        // NG
  int*   pidx    = (int*)(bcat + NG);       // NB*NBLK
  int*   invalid = pidx + NB * NBLK;        // NB
  unsigned short* xh     = (unsigned short*)(invalid + NB);  // NB*KG bf16
  unsigned short* Wcat   = xh + (size_t)NB * KG;             // NGP*KG bf16
  unsigned short* outWb  = Wcat + (size_t)NGP * KG;          // NVP*KP bf16
  unsigned short* locenc = outWb + (size_t)NVP * KP;         // NS*NB*NENC bf16

  const size_t base_bytes =
      (size_t)(NB * NH + NB * NG + NB * NBLK + NG) * 4 +
      (size_t)(NB * NBLK + NB) * 4 +
      ((size_t)NB * KG + (size_t)NGP * KG + (size_t)NVP * KP) * 2;
  const size_t locenc_bytes = (size_t)NS * NB * NENC * 2;
  const bool use_locenc = (ws_size >= base_bytes + locenc_bytes);
  if (!use_locenc) locenc = nullptr;

  float* out = (float*)d_out;

  // zero recurrent state: xh (h/oe/pads) + c  (baseline-proven)
  hipMemsetAsync(xh, 0, sizeof(unsigned short) * (size_t)NB * KG, stream);
  hipMemsetAsync(c, 0, sizeof(float) * (size_t)NB * NH, stream);
  misc_kernel<<<(NB * NPE + 255) / 256, 256, 0, stream>>>(
      power_1h, power_W, power_b, loc_idxs, b_ih, b_hh, xh, bcat, invalid);
  prep_wcat_kernel<<<(NGP * KG + 255) / 256, 256, 0, stream>>>(W_ih, W_hh, Wcat);
  prep_outw_kernel<<<(NVP * KP + 255) / 256, 256, 0, stream>>>(out_W, outWb);
  if (use_locenc) {
    // one-time: all-steps alignment + loc_enc; also writes step-0 slice to xh
    locenc_kernel<<<NB, 256, 0, stream>>>(loc_idxs, MA, enc, locenc, xh);
  }

  // step keys (host-side threefry: deterministic, no device API)
  unsigned key[2 * NS];
  for (unsigned i = 0; i < NS; ++i) {
    unsigned y0, y1;
    threefry2x32(0u, 42u, i, i + NS, y0, y1);
    key[2 * i] = y0;
    threefry2x32(0u, 42u, i, i + NS, y0, y1);  // same block; lane1 of pair (i, i+NS)
    key[2 * i + 1] = y1;
  }

  dim3 gGates(NGP / 64, NB / 64);
  dim3 gScores(NBLK, NB / 64);
  for (int s = 0; s < NS; ++s) {
    if (!use_locenc) {
      build_x_kernel<<<NB, 256, 0, stream>>>(loc_idxs, MA, enc, xh, s);
    }
    gates_kernel<<<gGates, 256, 0, stream>>>(xh, Wcat, bcat, gates);
    lstm_cell_kernel<<<(NB * NH + 255) / 256, 256, 0, stream>>>(gates, xh, c);
    scores_kernel<<<gScores, 256, 0, stream>>>(
        xh, outWb, out_b, order_masks, invalid, out, pval, pidx,
        s, key[2 * s], key[2 * s + 1]);
    sample_kernel<<<NB, 256, 0, stream>>>(
        pval, pidx, order_embedding, locenc, xh, out, s);
  }
}